// Round 9
// baseline (154.619 us; speedup 1.0000x reference)
//
#include <hip/hip_runtime.h>
#include <cstdint>
#include <cstddef>

#define NN   2048
#define N2   (2048LL*2048LL)
#define CC   2
#define EE   5
#define WIN  512
#define WOUT 256

typedef __bf16 bf16_t;
typedef __attribute__((ext_vector_type(8))) __bf16 bf16x8;
typedef __attribute__((ext_vector_type(4))) __bf16 bf16x4;
typedef __attribute__((ext_vector_type(4))) float  f32x4;

#define AS1 __attribute__((address_space(1)))
#define AS3 __attribute__((address_space(3)))

// ---------------- prep: bf16 casts + gcn_w transpose-cast, one launch ----------------
__global__ void k_prep(const float* __restrict__ X, const float* __restrict__ l1w,
                       const float* __restrict__ l2w, const float* __restrict__ gcnw,
                       bf16_t* __restrict__ Xb, bf16_t* __restrict__ l1wb,
                       bf16_t* __restrict__ l2wb, bf16_t* __restrict__ gwT) {
  __shared__ bf16_t tile[64][65];
  int bid = blockIdx.x;
  if (bid < 608) {
    int i = bid * 256 + threadIdx.x;
    const float* src; bf16_t* dst; int off;
    if (i < 131072)      { src = X;   dst = Xb;   off = i; }
    else if (i < 147456) { src = l1w; dst = l1wb; off = i - 131072; }
    else if (i < 155648) { src = l2w; dst = l2wb; off = i - 147456; }
    else return;
    float4 a = ((const float4*)src)[off * 2];
    float4 b = ((const float4*)src)[off * 2 + 1];
    bf16x8 o;
    o[0] = (bf16_t)a.x; o[1] = (bf16_t)a.y; o[2] = (bf16_t)a.z; o[3] = (bf16_t)a.w;
    o[4] = (bf16_t)b.x; o[5] = (bf16_t)b.y; o[6] = (bf16_t)b.z; o[7] = (bf16_t)b.w;
    ((bf16x8*)dst)[off] = o;
  } else {
    int b2 = bid - 608;              // 0..31
    int m0 = (b2 & 7) * 64, n0 = (b2 >> 3) * 64;
    int t = threadIdx.x, tr = t >> 4, tc = (t & 15) << 2;
#pragma unroll
    for (int v = 0; v < 4; ++v) {
      int r = tr + v * 16;
      float4 d = *(const float4*)&gcnw[(long long)(m0 + r) * WOUT + n0 + tc];
      tile[r][tc + 0] = (bf16_t)d.x; tile[r][tc + 1] = (bf16_t)d.y;
      tile[r][tc + 2] = (bf16_t)d.z; tile[r][tc + 3] = (bf16_t)d.w;
    }
    __syncthreads();
#pragma unroll
    for (int v = 0; v < 4; ++v) {
      int r = tr + v * 16;
      bf16x4 o;
      o[0] = tile[tc + 0][r]; o[1] = tile[tc + 1][r];
      o[2] = tile[tc + 2][r]; o[3] = tile[tc + 3][r];
      *(bf16x4*)&gwT[(long long)(n0 + r) * WIN + m0 + tc] = o;
    }
  }
}

// ---------------- combine: single A pass; Hb via LDS, Hb2 carried in registers ----------------

__global__ void k_combine(const float* __restrict__ A,
                          const float* __restrict__ w0a, const float* __restrict__ w0b,
                          const float* __restrict__ w1,
                          bf16_t* __restrict__ Ha, bf16_t* __restrict__ HbT,
                          bf16_t* __restrict__ Hb2T, float* __restrict__ part) {
  __shared__ bf16_t tl[2][64][65];
  __shared__ float cs[2][16][64];
  float f[3][2][5];
  {
    const float* wp[3] = {w0a, w0b, w1};
#pragma unroll
    for (int w = 0; w < 3; ++w)
#pragma unroll
      for (int c = 0; c < 2; ++c) {
        float x[5], m = -1e30f, s = 0.f;
#pragma unroll
        for (int e = 0; e < 5; ++e) { x[e] = wp[w][c * 5 + e]; m = fmaxf(m, x[e]); }
#pragma unroll
        for (int e = 0; e < 5; ++e) { x[e] = expf(x[e] - m); s += x[e]; }
#pragma unroll
        for (int e = 0; e < 5; ++e) f[w][c][e] = x[e] / s;
      }
  }
  int i0 = blockIdx.x * 64, j0 = blockIdx.y * 64;
  int t = threadIdx.x, tr = t >> 4, tc = (t & 15) << 2;
  float cs0[4] = {0, 0, 0, 0}, cs1[4] = {0, 0, 0, 0};
  bf16x4 hb2a[4], hb2b[4];

#pragma unroll
  for (int v = 0; v < 4; ++v) {
    int lr = tr + v * 16;
    long long gi = i0 + lr;
    const float* base = A + gi * (long long)NN + j0 + tc;
    float av[5][4];
#pragma unroll
    for (int e = 0; e < 5; ++e) {
      float4 q = *(const float4*)(base + (long long)e * N2);
      av[e][0] = q.x; av[e][1] = q.y; av[e][2] = q.z; av[e][3] = q.w;
    }
    bf16x4 ha0, ha1;
#pragma unroll
    for (int x = 0; x < 4; ++x) {
      float s0 = 0.f, s1 = 0.f, s2 = 0.f, s3 = 0.f, s4 = 0.f, s5 = 0.f;
#pragma unroll
      for (int e = 0; e < 5; ++e) {
        float u = av[e][x];
        s0 += f[0][0][e] * u; s1 += f[0][1][e] * u;
        s2 += f[1][0][e] * u; s3 += f[1][1][e] * u;
        s4 += f[2][0][e] * u; s5 += f[2][1][e] * u;
      }
      ha0[x] = (bf16_t)s0; cs0[x] += (float)ha0[x];
      ha1[x] = (bf16_t)s1; cs1[x] += (float)ha1[x];
      tl[0][lr][tc + x] = (bf16_t)s2; tl[1][lr][tc + x] = (bf16_t)s3;
      hb2a[v][x] = (bf16_t)s4; hb2b[v][x] = (bf16_t)s5;
    }
    *(bf16x4*)&Ha[0 * N2 + gi * NN + j0 + tc] = ha0;
    *(bf16x4*)&Ha[1 * N2 + gi * NN + j0 + tc] = ha1;
  }
#pragma unroll
  for (int x = 0; x < 4; ++x) { cs[0][tr][tc + x] = cs0[x]; cs[1][tr][tc + x] = cs1[x]; }
  __syncthreads();

#pragma unroll
  for (int v = 0; v < 4; ++v) {
    int lr = tr + v * 16;
#pragma unroll
    for (int ch = 0; ch < 2; ++ch) {
      bf16x4 o;
      o[0] = tl[ch][tc + 0][lr]; o[1] = tl[ch][tc + 1][lr];
      o[2] = tl[ch][tc + 2][lr]; o[3] = tl[ch][tc + 3][lr];
      *(bf16x4*)&HbT[(long long)ch * N2 + (long long)(j0 + lr) * NN + i0 + tc] = o;
    }
  }
  if (t < 128) {
    int ch = t >> 6, col = t & 63;
    float s = 0.f;
#pragma unroll
    for (int r = 0; r < 16; ++r) s += cs[ch][r][col];
    part[((long long)ch * 32 + blockIdx.x) * NN + j0 + col] = s;
  }
  __syncthreads();

#pragma unroll
  for (int v = 0; v < 4; ++v) {
    int lr = tr + v * 16;
#pragma unroll
    for (int x = 0; x < 4; ++x) {
      tl[0][lr][tc + x] = hb2a[v][x];
      tl[1][lr][tc + x] = hb2b[v][x];
    }
  }
  __syncthreads();

#pragma unroll
  for (int v = 0; v < 4; ++v) {
    int lr = tr + v * 16;
#pragma unroll
    for (int ch = 0; ch < 2; ++ch) {
      bf16x4 o;
      o[0] = tl[ch][tc + 0][lr]; o[1] = tl[ch][tc + 1][lr];
      o[2] = tl[ch][tc + 2][lr]; o[3] = tl[ch][tc + 3][lr];
      *(bf16x4*)&Hb2T[(long long)ch * N2 + (long long)(j0 + lr) * NN + i0 + tc] = o;
    }
  }
}

__global__ void k_s_finish(const float* __restrict__ part, float* __restrict__ s) {
  int idx = blockIdx.x * 256 + threadIdx.x;
  int c = idx >> 11, k = idx & 2047;
  float acc = 0.f;
#pragma unroll
  for (int ib = 0; ib < 32; ++ib) acc += part[((long long)c * 32 + ib) * NN + k];
  s[idx] = acc;
}

// deg[c][j] = sum_k (svec[k] - A[j,k])*BT[j,k];  Mdiag[c][j] = sum_k A[j,k]*BT[j,k]
template<bool EMIT_DIS>
__global__ void k_deg(const float* __restrict__ svec, const bf16_t* __restrict__ Arows,
                      const bf16_t* __restrict__ BT,
                      float* __restrict__ out1, float* __restrict__ out2,
                      float* __restrict__ out3) {
  int c = blockIdx.y;
  int j = blockIdx.x * 4 + (threadIdx.x >> 6);
  int lane = threadIdx.x & 63;
  const bf16_t* a = Arows + (long long)c * N2 + (long long)j * NN;
  const bf16_t* b = BT + (long long)c * N2 + (long long)j * NN;
  const float* s = svec + c * NN;
  float acc_s = 0.f, acc_a = 0.f;
#pragma unroll
  for (int it = 0; it < 4; ++it) {
    int k0 = (lane + it * 64) * 8;
    bf16x8 av = *(const bf16x8*)(a + k0);
    bf16x8 bv = *(const bf16x8*)(b + k0);
    float4 s0 = *(const float4*)(s + k0);
    float4 s1 = *(const float4*)(s + k0 + 4);
    float sv[8] = {s0.x, s0.y, s0.z, s0.w, s1.x, s1.y, s1.z, s1.w};
#pragma unroll
    for (int x = 0; x < 8; ++x) {
      float bx = (float)bv[x];
      acc_s += sv[x] * bx;
      acc_a += (float)av[x] * bx;
    }
  }
#pragma unroll
  for (int o = 32; o > 0; o >>= 1) {
    acc_s += __shfl_xor(acc_s, o, 64);
    acc_a += __shfl_xor(acc_a, o, 64);
  }
  if (lane == 0) {
    float deg = acc_s - acc_a;
    bool nz = (deg != 0.f);
    if (!EMIT_DIS) {
      out1[c * NN + j] = nz ? 1.f / deg : 0.f;
      out2[c * NN + j] = nz ? 1.f : 0.f;
    } else {
      float dis = nz ? 0.70710678118654752f : 1.f;
      out1[c * NN + j] = nz ? dis / deg : 0.f;     // cscal = dis/deg2
      out2[c * NN + j] = dis;                      // disv
      out3[c * NN + j] = acc_a;                    // Mdiag = diag(Hn@Hb2)
    }
  }
}

// XWdT[c][f][i] = XWT[f][i] * disv[c][i]
__global__ void k_scale_xwd(const bf16_t* __restrict__ XWT, const float* __restrict__ disv,
                            bf16_t* __restrict__ XWdT) {
  int i = blockIdx.x * 256 + threadIdx.x;
  int c = i >> 16, rem = i & 65535;
  bf16x8 v = ((const bf16x8*)XWT)[rem];
  int col0 = (rem & 255) * 8;
  float4 d0 = *(const float4*)(disv + c * NN + col0);
  float4 d1 = *(const float4*)(disv + c * NN + col0 + 4);
  bf16x8 o;
  o[0] = (bf16_t)((float)v[0] * d0.x); o[1] = (bf16_t)((float)v[1] * d0.y);
  o[2] = (bf16_t)((float)v[2] * d0.z); o[3] = (bf16_t)((float)v[3] * d0.w);
  o[4] = (bf16_t)((float)v[4] * d1.x); o[5] = (bf16_t)((float)v[5] * d1.y);
  o[6] = (bf16_t)((float)v[6] * d1.z); o[7] = (bf16_t)((float)v[7] * d1.w);
  ((bf16x8*)XWdT)[i] = o;
}

// ---------------- GEMM1: 256x128 block, 4 waves, wave tile 128x64 (acc 8x4) ----------------
// Ring-3 of BK32 slots (A 256x32 + B 128x32 = 24KB), counted vmcnt 12/6/0, chunk-XOR swizzle.
// LDS reads/MFMA = 12/32 = 0.375 (vs 0.5 at 64x64 wave tile) -> LDS traffic below matrix-pipe.

__global__ __launch_bounds__(256, 1)
void k_gemmL(const bf16_t* __restrict__ A, const bf16_t* __restrict__ B,
             bf16_t* __restrict__ Hn, bf16_t* __restrict__ HnT,
             const float* __restrict__ dinv) {
  __shared__ __align__(16) char smem[73728];  // 3 x 24576
  bf16_t* tile = (bf16_t*)smem;               // epilogue reuse: 128x130 bf16 = 33.3KB

  int cz = blockIdx.z;
  const bf16_t* Ab = A + cz * N2 + (long long)blockIdx.x * 256 * NN;
  const bf16_t* Bb = B + cz * N2 + (long long)blockIdx.y * 128 * NN;

  int t = threadIdx.x, wid = t >> 6, lane = t & 63;
  int wr = wid >> 1, wc = wid & 1;
  f32x4 acc[8][4] = {};
  int frow = lane & 15;
  int fk_sw = (((lane >> 4) ^ ((frow >> 1) & 3)) << 3);
  int srow = t >> 2;                                // 0..63
  int scol_sw = (((t & 3) ^ ((t >> 3) & 3)) << 3);  // XOR uses (row>>1)&3; 64-row passes preserve it

  auto STAGE = [&](int TT, int BUF) {
    long long kko = (long long)TT * 32 + scol_sw;
    const bf16_t* ga = Ab + (long long)srow * NN + kko;
    const bf16_t* gb = Bb + (long long)srow * NN + kko;
    char* la = smem + BUF * 24576 + wid * 1024;
    char* lb = smem + BUF * 24576 + 16384 + wid * 1024;
#pragma unroll
    for (int p2 = 0; p2 < 4; ++p2)
      __builtin_amdgcn_global_load_lds((AS1 void*)(ga + (long long)(p2 * 64) * NN),
          (AS3 void*)(la + p2 * 4096), 16, 0, 0);
#pragma unroll
    for (int p2 = 0; p2 < 2; ++p2)
      __builtin_amdgcn_global_load_lds((AS1 void*)(gb + (long long)(p2 * 64) * NN),
          (AS3 void*)(lb + p2 * 4096), 16, 0, 0);
  };
  auto COMPUTE = [&](int BUF) {
    const bf16_t* As = (const bf16_t*)(smem + BUF * 24576);
    const bf16_t* Bs = (const bf16_t*)(smem + BUF * 24576 + 16384);
    bf16x8 af[8], bfr[4];
#pragma unroll
    for (int m = 0; m < 8; ++m)
      af[m] = *(const bf16x8*)&As[(wr * 128 + m * 16 + frow) * 32 + fk_sw];
#pragma unroll
    for (int n = 0; n < 4; ++n)
      bfr[n] = *(const bf16x8*)&Bs[(wc * 64 + n * 16 + frow) * 32 + fk_sw];
    __builtin_amdgcn_s_setprio(1);
#pragma unroll
    for (int m = 0; m < 8; ++m)
#pragma unroll
      for (int n = 0; n < 4; ++n)
        acc[m][n] = __builtin_amdgcn_mfma_f32_16x16x32_bf16(af[m], bfr[n], acc[m][n], 0, 0, 0);
    __builtin_amdgcn_s_setprio(0);
  };

  const int nt = 64;  // K / 32
  STAGE(0, 0); STAGE(1, 1); STAGE(2, 2);
  int slot = 0;
  for (int tt = 0; tt < nt; ++tt) {
    int rem = nt - 1 - tt;
    if (rem >= 2)      asm volatile("s_waitcnt vmcnt(12)" ::: "memory");
    else if (rem == 1) asm volatile("s_waitcnt vmcnt(6)" ::: "memory");
    else               asm volatile("s_waitcnt vmcnt(0)" ::: "memory");
    __builtin_amdgcn_s_barrier();
    __builtin_amdgcn_sched_barrier(0);
    COMPUTE(slot);
    __builtin_amdgcn_s_barrier();
    if (tt + 3 < nt) STAGE(tt + 3, slot);
    slot = (slot == 2) ? 0 : slot + 1;
  }
  __builtin_amdgcn_sched_barrier(0);

  // C/D frag: col = lane&15, row = (lane>>4)*4 + reg
  int rl0 = wr * 128 + ((lane >> 4) << 2);          // local row in 256
  int cl0 = wc * 64 + (lane & 15);                  // local col in 128
  int r0 = blockIdx.x * 256 + rl0;
  int c0 = blockIdx.y * 128 + cl0;

  bf16_t* Cb = Hn + cz * N2;
  bf16_t* Ct = HnT + cz * N2;
  float dj[4];
#pragma unroll
  for (int n = 0; n < 4; ++n) dj[n] = dinv[cz * NN + c0 + n * 16];

  // Hn (row-major) direct write
#pragma unroll
  for (int m = 0; m < 8; ++m)
#pragma unroll
    for (int n = 0; n < 4; ++n)
#pragma unroll
      for (int j = 0; j < 4; ++j) {
        int r = r0 + m * 16 + j, col = c0 + n * 16;
        float v = (r == col) ? 0.f : acc[m][n][j] * dj[n];
        Cb[(long long)r * NN + col] = (bf16_t)v;
      }

  // HnT via two 128x128 LDS-transpose halves (half h = rows h*128..h*128+127 of the block)
  int rt0 = ((lane >> 4) << 2);
#pragma unroll
  for (int h = 0; h < 2; ++h) {
    __syncthreads();
    if (wr == h) {
#pragma unroll
      for (int m = 0; m < 8; ++m)
#pragma unroll
        for (int n = 0; n < 4; ++n)
#pragma unroll
          for (int j = 0; j < 4; ++j) {
            int r = r0 + m * 16 + j, col = c0 + n * 16;
            float v = (r == col) ? 0.f : acc[m][n][j] * dj[n];
            tile[(m * 16 + rt0 + j) * 130 + cl0 + n * 16] = (bf16_t)v;
          }
    }
    __syncthreads();
    int nl = t >> 5, rl = (t & 31) * 4;
#pragma unroll
    for (int vv = 0; vv < 16; ++vv) {
      int n_l = nl + vv * 8;
      bf16x4 o;
      o[0] = tile[(rl + 0) * 130 + n_l]; o[1] = tile[(rl + 1) * 130 + n_l];
      o[2] = tile[(rl + 2) * 130 + n_l]; o[3] = tile[(rl + 3) * 130 + n_l];
      *(bf16x4*)&Ct[(long long)(blockIdx.y * 128 + n_l) * NN + blockIdx.x * 256 + h * 128 + rl] = o;
    }
  }
}

// ---------------- bf16 GEMM, 128x64 tile, ring-3, counted vmcnt, swizzle, fused epilogues ----------------

enum { EP_F32 = 0, EP_BRELU = 3, EP_BF32 = 4, EP_XWT = 5, EP_BF16O = 7 };

template<int EP>
__global__ __launch_bounds__(256)
void k_gemm(const bf16_t* __restrict__ A, const bf16_t* __restrict__ B,
            void* __restrict__ Cv,
            const float* __restrict__ aux1, const float* __restrict__ aux2,
            bf16_t* __restrict__ aux3,
            int N, int K, int lda, int ldb,
            long long zA, long long zB, long long zC) {
  __shared__ __align__(16) char smem[36864];
  bf16_t* As = (bf16_t*)smem;
  bf16_t* Bs = (bf16_t*)(smem + 24576);
  bf16_t* tile = (bf16_t*)smem;

  int cz = blockIdx.z;
  const bf16_t* Ab = A + cz * zA + (long long)blockIdx.x * 128 * lda;
  const bf16_t* Bb = B + cz * zB + (long long)blockIdx.y * 64 * ldb;

  int t = threadIdx.x, wid = t >> 6, lane = t & 63;
  int wr = wid >> 1, wc = wid & 1;
  f32x4 acc[4][2] = {};
  int frow = lane & 15;
  int fk_sw = (((lane >> 4) ^ ((frow >> 1) & 3)) << 3);
  int srow = t >> 2;
  int scol_sw = (((t & 3) ^ ((t >> 3) & 3)) << 3);
  int nt = K >> 5;

  auto STAGE = [&](int TT, int BUF) {
    long long kko = (long long)TT * 32 + scol_sw;
    const bf16_t* ga0 = Ab + (long long)srow * lda + kko;
    const bf16_t* ga1 = Ab + (long long)(64 + srow) * lda + kko;
    const bf16_t* gb0 = Bb + (long long)srow * ldb + kko;
    char* la = smem + BUF * 8192 + wid * 1024;
    char* lb = smem + 24576 + BUF * 4096 + wid * 1024;
    __builtin_amdgcn_global_load_lds((AS1 void*)ga0, (AS3 void*)la, 16, 0, 0);
    __builtin_amdgcn_global_load_lds((AS1 void*)ga1, (AS3 void*)(la + 4096), 16, 0, 0);
    __builtin_amdgcn_global_load_lds((AS1 void*)gb0, (AS3 void*)lb, 16, 0, 0);
  };
  auto COMPUTE = [&](int BUF) {
    bf16x8 af[4], bfr[2];
#pragma unroll
    for (int m = 0; m < 4; ++m)
      af[m] = *(const bf16x8*)&As[BUF * 4096 + (wr * 64 + m * 16 + frow) * 32 + fk_sw];
#pragma unroll
    for (int n = 0; n < 2; ++n)
      bfr[n] = *(const bf16x8*)&Bs[BUF * 2048 + (wc * 32 + n * 16 + frow) * 32 + fk_sw];
#pragma unroll
    for (int m = 0; m < 4; ++m)
#pragma unroll
      for (int n = 0; n < 2; ++n)
        acc[m][n] = __builtin_amdgcn_mfma_f32_16x16x32_bf16(af[m], bfr[n], acc[m][n], 0, 0, 0);
  };

  STAGE(0, 0); STAGE(1, 1); STAGE(2, 2);
  int slot = 0;
  for (int tt = 0; tt < nt; ++tt) {
    int rem = nt - 1 - tt;
    if (rem >= 2)      asm volatile("s_waitcnt vmcnt(6)" ::: "memory");
    else if (rem == 1) asm volatile("s_waitcnt vmcnt(3)" ::: "memory");
    else               asm volatile("s_waitcnt vmcnt(0)" ::: "memory");
    __builtin_amdgcn_s_barrier();
    __builtin_amdgcn_sched_barrier(0);
    COMPUTE(slot);
    __builtin_amdgcn_s_barrier();
    if (tt + 3 < nt) STAGE(tt + 3, slot);
    slot = (slot == 2) ? 0 : slot + 1;
  }
  __builtin_amdgcn_sched_barrier(0);

  int rl0 = wr * 64 + ((lane >> 4) << 2);
  int cl0 = wc * 32 + (lane & 15);
  int r0 = blockIdx.x * 128 + rl0;
  int c0 = blockIdx.y * 64 + cl0;

  if constexpr (EP == EP_F32) {
    float* Cb = (float*)Cv + cz * zC;
#pragma unroll
    for (int m = 0; m < 4; ++m)
#pragma unroll
      for (int n = 0; n < 2; ++n)
#pragma unroll
        for (int j = 0; j < 4; ++j)
          Cb[(long long)(r0 + m * 16 + j) * N + c0 + n * 16] = acc[m][n][j];
  } else if constexpr (EP == EP_BF16O) {
    bf16_t* Cb = (bf16_t*)Cv + cz * zC;
#pragma unroll
    for (int m = 0; m < 4; ++m)
#pragma unroll
      for (int n = 0; n < 2; ++n)
#pragma unroll
        for (int j = 0; j < 4; ++j)
          Cb[(long long)(r0 + m * 16 + j) * N + c0 + n * 16] = (bf16_t)acc[m][n][j];
  } else if constexpr (EP == EP_XWT) {
    float* Cb = (float*)Cv;
#pragma unroll
    for (int m = 0; m < 4; ++m)
#pragma unroll
      for (int n = 0; n < 2; ++n)
#pragma unroll
        for (int j = 0; j < 4; ++j) {
          float v = acc[m][n][j];
          Cb[(long long)(r0 + m * 16 + j) * N + c0 + n * 16] = v;
          tile[(rl0 + m * 16 + j) * 65 + cl0 + n * 16] = (bf16_t)v;
        }
    __syncthreads();
    int nl = t >> 5, rl = (t & 31) * 4;
#pragma unroll
    for (int vv = 0; vv < 8; ++vv) {
      int n_l = nl + vv * 8;
      bf16x4 o;
      o[0] = tile[(rl + 0) * 65 + n_l]; o[1] = tile[(rl + 1) * 65 + n_l];
      o[2] = tile[(rl + 2) * 65 + n_l]; o[3] = tile[(rl + 3) * 65 + n_l];
      *(bf16x4*)&aux3[(long long)(blockIdx.y * 64 + n_l) * NN + blockIdx.x * 128 + rl] = o;
    }
  } else if constexpr (EP == EP_BRELU) {
    bf16_t* Cb = (bf16_t*)Cv;
    float bj[2];
#pragma unroll
    for (int n = 0; n < 2; ++n) bj[n] = aux1[c0 + n * 16];
#pragma unroll
    for (int m = 0; m < 4; ++m)
#pragma unroll
      for (int n = 0; n < 2; ++n)
#pragma unroll
        for (int j = 0; j < 4; ++j)
          Cb[(long long)(r0 + m * 16 + j) * N + c0 + n * 16] =
              (bf16_t)fmaxf(acc[m][n][j] + bj[n], 0.f);
  } else { // EP_BF32
    float* Cb = (float*)Cv;
    float bj[2];
#pragma unroll
    for (int n = 0; n < 2; ++n) bj[n] = aux1[c0 + n * 16];
#pragma unroll
    for (int m = 0; m < 4; ++m)
#pragma unroll
      for (int n = 0; n < 2; ++n)
#pragma unroll
        for (int j = 0; j < 4; ++j)
          Cb[(long long)(r0 + m * 16 + j) * N + c0 + n * 16] = acc[m][n][j] + bj[n];
  }
}

// ---------------- GCN epilogue: out = relu(cscal*(Z - Mdiag*dis*XW) + dis^2*XW + b) ----------------

__global__ void k_gcn_epi2(const float* __restrict__ Z, const float* __restrict__ XW,
                           const float* __restrict__ gcn_b, const float* __restrict__ cscal,
                           const float* __restrict__ disv, const float* __restrict__ Mdiag,
                           bf16_t* __restrict__ Xcat) {
  long long idx4 = ((long long)blockIdx.x * 256 + threadIdx.x) * 4;
  int c = (int)(idx4 >> 19);
  int rem = (int)(idx4 & ((1 << 19) - 1));
  int n = rem >> 8, fcol = rem & 255;
  float4 z  = *(const float4*)(Z + (long long)c * NN * WOUT + rem);
  float4 xw = *(const float4*)(XW + rem);
  float4 b  = *(const float4*)(gcn_b + fcol);
  float cs = cscal[c * NN + n], dn = disv[c * NN + n], md = Mdiag[c * NN + n];
  float d2 = dn * dn, mdd = md * dn;
  bf16x4 o;
  o[0] = (bf16_t)fmaxf(cs * (z.x - mdd * xw.x) + d2 * xw.x + b.x, 0.f);
  o[1] = (bf16_t)fmaxf(cs * (z.y - mdd * xw.y) + d2 * xw.y + b.y, 0.f);
  o[2] = (bf16_t)fmaxf(cs * (z.z - mdd * xw.z) + d2 * xw.z + b.z, 0.f);
  o[3] = (bf16_t)fmaxf(cs * (z.w - mdd * xw.w) + d2 * xw.w + b.w, 0.f);
  *(bf16x4*)&Xcat[(long long)n * (CC * WOUT) + c * WOUT + fcol] = o;
}

// ---------------- launch ----------------

extern "C" void kernel_launch(void* const* d_in, const int* in_sizes, int n_in,
                              void* d_out, int out_size, void* d_ws, size_t ws_size,
                              hipStream_t stream) {
  const float* A    = (const float*)d_in[0];
  const float* X    = (const float*)d_in[1];
  const float* w0a  = (const float*)d_in[2];
  const float* w0b  = (const float*)d_in[3];
  const float* w1   = (const float*)d_in[4];
  const float* gcnw = (const float*)d_in[5];
  const float* gcnb = (const float*)d_in[6];
  const float* l1w  = (const float*)d_in[7];
  const float* l1b  = (const float*)d_in[8];
  const float* l2w  = (const float*)d_in[9];
  const float* l2b  = (const float*)d_in[10];
  float* out = (float*)d_out;

  char* p = (char*)d_ws;
  auto carve = [&](size_t bytes) -> char* {
    char* r = p; p += (bytes + 255) & ~(size_t)255; return r;
  };
  float*  svec  = (float*)carve((size_t)CC * NN * 4);
  float*  dinv1 = (float*)carve((size_t)CC * NN * 4);
  float*  m1    = (float*)carve((size_t)CC * NN * 4);
  float*  cscal = (float*)carve((size_t)CC * NN * 4);
  float*  disv  = (float*)carve((size_t)CC * NN * 4);
  float*  Mdiag = (float*)carve((size_t)CC * NN * 4);
  float*  part  = (float*)carve((size_t)CC * 32 * NN * 4);
  bf16_t* S1    = (bf16_t*)carve((size_t)CC * N2 * 2); // Ha -> {XWdT, Yt, Z}
  bf16_t* HbT   = (bf16_t*)carve((size_t)CC * N2 * 2);
  bf16_t* Hb2T  = (bf16_t*)carve((size_t)CC * N2 * 2);
  bf16_t* Hn    = (bf16_t*)carve((size_t)CC * N2 * 2);
  bf16_t* HnT   = (bf16_t*)carve((size_t)CC * N2 * 2);
  bf16_t* Xb    = (bf16_t*)carve((size_t)NN * WIN * 2);
  bf16_t* gwT   = (bf16_t*)carve((size_t)WOUT * WIN * 2);
  bf16_t* l1wb  = (bf16_t*)carve((size_t)WOUT * CC * WOUT * 2);
  bf16_t* l2wb  = (bf16_t*)carve((size_t)WOUT * WOUT * 2);
  float*  XW    = (float*)carve((size_t)NN * WOUT * 4);
  bf16_t* XWT   = (bf16_t*)carve((size_t)WOUT * NN * 2);
  bf16_t* Xcat  = (bf16_t*)carve((size_t)NN * CC * WOUT * 2);
  bf16_t* hb    = (bf16_t*)carve((size_t)NN * WOUT * 2);

  bf16_t* Ha = S1;
  bf16_t* XWdT = (bf16_t*)((char*)S1);
  bf16_t* Yt   = (bf16_t*)((char*)S1 + (2LL << 20));
  float*  Z    = (float*) ((char*)S1 + (6LL << 20));

  // prep
  k_prep<<<640, 256, 0, stream>>>(X, l1w, l2w, gcnw, Xb, l1wb, l2wb, gwT);
  k_combine<<<dim3(32, 32), 256, 0, stream>>>(A, w0a, w0b, w1, Ha, HbT, Hb2T, part);
  k_s_finish<<<16, 256, 0, stream>>>(part, svec);

  // layer 0: analytic degrees; GEMM1 (256x128 block, acc 8x4) fused normalize -> Hn + HnT
  k_deg<false><<<dim3(512, 2), 256, 0, stream>>>(svec, Ha, HbT, dinv1, m1, nullptr);
  k_gemmL<<<dim3(8, 16, 2), 256, 0, stream>>>(Ha, HbT, Hn, HnT, dinv1);

  // layer 1 scalars: deg2 (-> cscal, disv) and Mdiag from one row-dot pass
  k_deg<true><<<dim3(512, 2), 256, 0, stream>>>(m1, Hn, Hb2T, cscal, disv, Mdiag);

  // GCN via associativity
  k_gemm<EP_XWT><<<dim3(16, 4, 1), 256, 0, stream>>>(
      Xb, gwT, XW, nullptr, nullptr, XWT, WOUT, WIN, WIN, WIN, 0, 0, 0);
  k_scale_xwd<<<512, 256, 0, stream>>>(XWT, disv, XWdT);
  k_gemm<EP_BF16O><<<dim3(2, 32, 2), 256, 0, stream>>>(
      XWdT, HnT, Yt, nullptr, nullptr, nullptr, NN, NN, NN, NN,
      (long long)WOUT * NN, N2, (long long)WOUT * NN);
  k_gemm<EP_F32><<<dim3(16, 4, 2), 256, 0, stream>>>(
      Hb2T, Yt, Z, nullptr, nullptr, nullptr, WOUT, NN, NN, NN,
      N2, (long long)WOUT * NN, (long long)NN * WOUT);
  k_gcn_epi2<<<1024, 256, 0, stream>>>(Z, XW, gcnb, cscal, disv, Mdiag, Xcat);

  // MLP with fused bias(+relu)
  k_gemm<EP_BRELU><<<dim3(16, 4, 1), 256, 0, stream>>>(
      Xcat, l1wb, hb, l1b, nullptr, nullptr, WOUT, CC * WOUT, CC * WOUT, CC * WOUT, 0, 0, 0);
  k_gemm<EP_BF32><<<dim3(16, 4, 1), 256, 0, stream>>>(
      hb, l2wb, out, l2b, nullptr, nullptr, WOUT, WOUT, WOUT, WOUT, 0, 0, 0);
}

// Round 10
// 143.960 us; speedup vs baseline: 1.0740x; 1.0740x over previous
//
#include <hip/hip_runtime.h>
#include <cstdint>
#include <cstddef>

#define NN   2048
#define N2   (2048LL*2048LL)
#define CC   2
#define EE   5
#define WIN  512
#define WOUT 256

typedef __bf16 bf16_t;
typedef __attribute__((ext_vector_type(8))) __bf16 bf16x8;
typedef __attribute__((ext_vector_type(4))) __bf16 bf16x4;
typedef __attribute__((ext_vector_type(4))) float  f32x4;

#define AS1 __attribute__((address_space(1)))
#define AS3 __attribute__((address_space(3)))

// ---------------- combine (+merged prep): single A pass; Hb via LDS, Hb2 in registers ----------------
// grid: 1024 combine blocks + 640 prep blocks (1D, 1664)

__global__ void k_combine(const float* __restrict__ A,
                          const float* __restrict__ w0a, const float* __restrict__ w0b,
                          const float* __restrict__ w1,
                          bf16_t* __restrict__ Ha, bf16_t* __restrict__ HbT,
                          bf16_t* __restrict__ Hb2T, float* __restrict__ part,
                          const float* __restrict__ X, const float* __restrict__ l1w,
                          const float* __restrict__ l2w, const float* __restrict__ gcnw,
                          bf16_t* __restrict__ Xb, bf16_t* __restrict__ l1wb,
                          bf16_t* __restrict__ l2wb, bf16_t* __restrict__ gwT) {
  __shared__ bf16_t tl[2][64][65];   // 16.6 KB
  __shared__ float cs[2][4][64];     // 2 KB (per-wave colsum partials)
  int bid = blockIdx.x;
  int t = threadIdx.x;

  if (bid >= 1024) {
    // ---- prep path ----
    int bid2 = bid - 1024;
    if (bid2 < 608) {
      int i = bid2 * 256 + t;
      const float* src; bf16_t* dst; int off;
      if (i < 131072)      { src = X;   dst = Xb;   off = i; }
      else if (i < 147456) { src = l1w; dst = l1wb; off = i - 131072; }
      else                 { src = l2w; dst = l2wb; off = i - 147456; }
      float4 a = ((const float4*)src)[off * 2];
      float4 b = ((const float4*)src)[off * 2 + 1];
      bf16x8 o;
      o[0] = (bf16_t)a.x; o[1] = (bf16_t)a.y; o[2] = (bf16_t)a.z; o[3] = (bf16_t)a.w;
      o[4] = (bf16_t)b.x; o[5] = (bf16_t)b.y; o[6] = (bf16_t)b.z; o[7] = (bf16_t)b.w;
      ((bf16x8*)dst)[off] = o;
    } else {
      int b2 = bid2 - 608;             // 0..31
      int m0 = (b2 & 7) * 64, n0 = (b2 >> 3) * 64;
      int tr = t >> 4, tc = (t & 15) << 2;
      bf16_t (*tile)[65] = (bf16_t (*)[65])&tl[0][0][0];
#pragma unroll
      for (int v = 0; v < 4; ++v) {
        int r = tr + v * 16;
        float4 d = *(const float4*)&gcnw[(long long)(m0 + r) * WOUT + n0 + tc];
        tile[r][tc + 0] = (bf16_t)d.x; tile[r][tc + 1] = (bf16_t)d.y;
        tile[r][tc + 2] = (bf16_t)d.z; tile[r][tc + 3] = (bf16_t)d.w;
      }
      __syncthreads();
#pragma unroll
      for (int v = 0; v < 4; ++v) {
        int r = tr + v * 16;
        bf16x4 o;
        o[0] = tile[tc + 0][r]; o[1] = tile[tc + 1][r];
        o[2] = tile[tc + 2][r]; o[3] = tile[tc + 3][r];
        *(bf16x4*)&gwT[(long long)(n0 + r) * WIN + m0 + tc] = o;
      }
    }
    return;
  }

  // ---- combine path ----
  float f[3][2][5];
  {
    const float* wp[3] = {w0a, w0b, w1};
#pragma unroll
    for (int w = 0; w < 3; ++w)
#pragma unroll
      for (int c = 0; c < 2; ++c) {
        float x[5], m = -1e30f, s = 0.f;
#pragma unroll
        for (int e = 0; e < 5; ++e) { x[e] = wp[w][c * 5 + e]; m = fmaxf(m, x[e]); }
#pragma unroll
        for (int e = 0; e < 5; ++e) { x[e] = expf(x[e] - m); s += x[e]; }
#pragma unroll
        for (int e = 0; e < 5; ++e) f[w][c][e] = x[e] / s;
      }
  }
  int i0 = (bid >> 5) * 64, j0 = (bid & 31) * 64;
  int tr = t >> 4, tc = (t & 15) << 2;
  int lane = t & 63, wid = t >> 6;
  float cs0[4] = {0, 0, 0, 0}, cs1[4] = {0, 0, 0, 0};
  bf16x4 hb2a[4], hb2b[4];

#pragma unroll
  for (int v = 0; v < 4; ++v) {
    int lr = tr + v * 16;
    long long gi = i0 + lr;
    const float* base = A + gi * (long long)NN + j0 + tc;
    float av[5][4];
#pragma unroll
    for (int e = 0; e < 5; ++e) {
      float4 q = *(const float4*)(base + (long long)e * N2);
      av[e][0] = q.x; av[e][1] = q.y; av[e][2] = q.z; av[e][3] = q.w;
    }
    bf16x4 ha0, ha1;
#pragma unroll
    for (int x = 0; x < 4; ++x) {
      float s0 = 0.f, s1 = 0.f, s2 = 0.f, s3 = 0.f, s4 = 0.f, s5 = 0.f;
#pragma unroll
      for (int e = 0; e < 5; ++e) {
        float u = av[e][x];
        s0 += f[0][0][e] * u; s1 += f[0][1][e] * u;
        s2 += f[1][0][e] * u; s3 += f[1][1][e] * u;
        s4 += f[2][0][e] * u; s5 += f[2][1][e] * u;
      }
      ha0[x] = (bf16_t)s0; cs0[x] += (float)ha0[x];
      ha1[x] = (bf16_t)s1; cs1[x] += (float)ha1[x];
      tl[0][lr][tc + x] = (bf16_t)s2; tl[1][lr][tc + x] = (bf16_t)s3;
      hb2a[v][x] = (bf16_t)s4; hb2b[v][x] = (bf16_t)s5;
    }
    *(bf16x4*)&Ha[0 * N2 + gi * NN + j0 + tc] = ha0;
    *(bf16x4*)&Ha[1 * N2 + gi * NN + j0 + tc] = ha1;
  }
  // intra-wave reduce over lane>>4 (4 of the 16 row-groups per wave), then LDS
#pragma unroll
  for (int x = 0; x < 4; ++x) {
    float a0 = cs0[x], a1 = cs1[x];
    a0 += __shfl_xor(a0, 16, 64); a0 += __shfl_xor(a0, 32, 64);
    a1 += __shfl_xor(a1, 16, 64); a1 += __shfl_xor(a1, 32, 64);
    if ((lane >> 4) == 0) {
      cs[0][wid][(lane & 15) * 4 + x] = a0;
      cs[1][wid][(lane & 15) * 4 + x] = a1;
    }
  }
  __syncthreads();

#pragma unroll
  for (int v = 0; v < 4; ++v) {
    int lr = tr + v * 16;
#pragma unroll
    for (int ch = 0; ch < 2; ++ch) {
      bf16x4 o;
      o[0] = tl[ch][tc + 0][lr]; o[1] = tl[ch][tc + 1][lr];
      o[2] = tl[ch][tc + 2][lr]; o[3] = tl[ch][tc + 3][lr];
      *(bf16x4*)&HbT[(long long)ch * N2 + (long long)(j0 + lr) * NN + i0 + tc] = o;
    }
  }
  if (t < 128) {
    int ch = t >> 6, col = t & 63;
    float s = cs[ch][0][col] + cs[ch][1][col] + cs[ch][2][col] + cs[ch][3][col];
    part[((long long)ch * 32 + (bid >> 5)) * NN + j0 + col] = s;
  }
  __syncthreads();

#pragma unroll
  for (int v = 0; v < 4; ++v) {
    int lr = tr + v * 16;
#pragma unroll
    for (int x = 0; x < 4; ++x) {
      tl[0][lr][tc + x] = hb2a[v][x];
      tl[1][lr][tc + x] = hb2b[v][x];
    }
  }
  __syncthreads();

#pragma unroll
  for (int v = 0; v < 4; ++v) {
    int lr = tr + v * 16;
#pragma unroll
    for (int ch = 0; ch < 2; ++ch) {
      bf16x4 o;
      o[0] = tl[ch][tc + 0][lr]; o[1] = tl[ch][tc + 1][lr];
      o[2] = tl[ch][tc + 2][lr]; o[3] = tl[ch][tc + 3][lr];
      *(bf16x4*)&Hb2T[(long long)ch * N2 + (long long)(j0 + lr) * NN + i0 + tc] = o;
    }
  }
}

__global__ void k_s_finish(const float* __restrict__ part, float* __restrict__ s) {
  int idx = blockIdx.x * 256 + threadIdx.x;
  int c = idx >> 11, k = idx & 2047;
  float acc = 0.f;
#pragma unroll
  for (int ib = 0; ib < 32; ++ib) acc += part[((long long)c * 32 + ib) * NN + k];
  s[idx] = acc;
}

// deg[c][j] = sum_k (svec[k] - A[j,k])*BT[j,k];  Mdiag[c][j] = sum_k A[j,k]*BT[j,k]
template<bool EMIT_DIS>
__global__ void k_deg(const float* __restrict__ svec, const bf16_t* __restrict__ Arows,
                      const bf16_t* __restrict__ BT,
                      float* __restrict__ out1, float* __restrict__ out2,
                      float* __restrict__ out3) {
  int c = blockIdx.y;
  int j = blockIdx.x * 4 + (threadIdx.x >> 6);
  int lane = threadIdx.x & 63;
  const bf16_t* a = Arows + (long long)c * N2 + (long long)j * NN;
  const bf16_t* b = BT + (long long)c * N2 + (long long)j * NN;
  const float* s = svec + c * NN;
  float acc_s = 0.f, acc_a = 0.f;
#pragma unroll
  for (int it = 0; it < 4; ++it) {
    int k0 = (lane + it * 64) * 8;
    bf16x8 av = *(const bf16x8*)(a + k0);
    bf16x8 bv = *(const bf16x8*)(b + k0);
    float4 s0 = *(const float4*)(s + k0);
    float4 s1 = *(const float4*)(s + k0 + 4);
    float sv[8] = {s0.x, s0.y, s0.z, s0.w, s1.x, s1.y, s1.z, s1.w};
#pragma unroll
    for (int x = 0; x < 8; ++x) {
      float bx = (float)bv[x];
      acc_s += sv[x] * bx;
      acc_a += (float)av[x] * bx;
    }
  }
#pragma unroll
  for (int o = 32; o > 0; o >>= 1) {
    acc_s += __shfl_xor(acc_s, o, 64);
    acc_a += __shfl_xor(acc_a, o, 64);
  }
  if (lane == 0) {
    float deg = acc_s - acc_a;
    bool nz = (deg != 0.f);
    if (!EMIT_DIS) {
      out1[c * NN + j] = nz ? 1.f / deg : 0.f;
      out2[c * NN + j] = nz ? 1.f : 0.f;
    } else {
      float dis = nz ? 0.70710678118654752f : 1.f;
      out1[c * NN + j] = nz ? dis / deg : 0.f;     // cscal
      out2[c * NN + j] = dis;                      // disv
      out3[c * NN + j] = acc_a;                    // Mdiag
    }
  }
}

// ---------------- GEMM1: 128x128 tile, BK=64 slots (2x BK32 sub-tiles), ring-2 (R8 config) ----------------

__global__ __launch_bounds__(256)
void k_gemmL(const bf16_t* __restrict__ A, const bf16_t* __restrict__ B,
             bf16_t* __restrict__ Hn, bf16_t* __restrict__ HnT,
             const float* __restrict__ dinv) {
  __shared__ __align__(16) char smem[65536];
  bf16_t* As = (bf16_t*)smem;
  bf16_t* Bs = (bf16_t*)(smem + 32768);
  bf16_t* tile = (bf16_t*)smem;

  int cz = blockIdx.z;
  const bf16_t* Ab = A + cz * N2 + (long long)blockIdx.x * 128 * NN;
  const bf16_t* Bb = B + cz * N2 + (long long)blockIdx.y * 128 * NN;

  int t = threadIdx.x, wid = t >> 6, lane = t & 63;
  int wr = wid >> 1, wc = wid & 1;
  f32x4 acc[4][4] = {};
  int frow = lane & 15;
  int fk_sw = (((lane >> 4) ^ ((frow >> 1) & 3)) << 3);
  int srow = t >> 2;
  int scol_sw = (((t & 3) ^ ((t >> 3) & 3)) << 3);

  auto STAGE = [&](int TT, int BUF) {
#pragma unroll
    for (int s = 0; s < 2; ++s) {
      long long kko = (long long)TT * 64 + s * 32 + scol_sw;
      const bf16_t* ga0 = Ab + (long long)srow * NN + kko;
      const bf16_t* gb0 = Bb + (long long)srow * NN + kko;
      char* la = smem + BUF * 16384 + s * 8192 + wid * 1024;
      char* lb = smem + 32768 + BUF * 16384 + s * 8192 + wid * 1024;
      __builtin_amdgcn_global_load_lds((AS1 void*)ga0, (AS3 void*)la, 16, 0, 0);
      __builtin_amdgcn_global_load_lds((AS1 void*)(ga0 + 64LL * NN), (AS3 void*)(la + 4096), 16, 0, 0);
      __builtin_amdgcn_global_load_lds((AS1 void*)gb0, (AS3 void*)lb, 16, 0, 0);
      __builtin_amdgcn_global_load_lds((AS1 void*)(gb0 + 64LL * NN), (AS3 void*)(lb + 4096), 16, 0, 0);
    }
  };
  auto COMPUTE = [&](int BUF) {
#pragma unroll
    for (int ks = 0; ks < 2; ++ks) {
      bf16x8 af[4], bfr[4];
#pragma unroll
      for (int m = 0; m < 4; ++m)
        af[m] = *(const bf16x8*)&As[BUF * 8192 + ks * 4096 + (wr * 64 + m * 16 + frow) * 32 + fk_sw];
#pragma unroll
      for (int n = 0; n < 4; ++n)
        bfr[n] = *(const bf16x8*)&Bs[BUF * 8192 + ks * 4096 + (wc * 64 + n * 16 + frow) * 32 + fk_sw];
      __builtin_amdgcn_s_setprio(1);
#pragma unroll
      for (int m = 0; m < 4; ++m)
#pragma unroll
        for (int n = 0; n < 4; ++n)
          acc[m][n] = __builtin_amdgcn_mfma_f32_16x16x32_bf16(af[m], bfr[n], acc[m][n], 0, 0, 0);
      __builtin_amdgcn_s_setprio(0);
    }
  };

  const int nt = 32;  // K/64
  STAGE(0, 0); STAGE(1, 1);
  for (int tt = 0; tt < nt; ++tt) {
    if (tt < nt - 1) asm volatile("s_waitcnt vmcnt(8)" ::: "memory");
    else             asm volatile("s_waitcnt vmcnt(0)" ::: "memory");
    __builtin_amdgcn_s_barrier();
    __builtin_amdgcn_sched_barrier(0);
    COMPUTE(tt & 1);
    __builtin_amdgcn_s_barrier();
    if (tt + 2 < nt) STAGE(tt + 2, tt & 1);
  }
  __builtin_amdgcn_sched_barrier(0);

  int rl0 = wr * 64 + ((lane >> 4) << 2);
  int cl0 = wc * 64 + (lane & 15);
  int r0 = blockIdx.x * 128 + rl0;
  int c0 = blockIdx.y * 128 + cl0;

  bf16_t* Cb = Hn + cz * N2;
  bf16_t* Ct = HnT + cz * N2;
  float dj[4];
#pragma unroll
  for (int n = 0; n < 4; ++n) dj[n] = dinv[cz * NN + c0 + n * 16];
#pragma unroll
  for (int m = 0; m < 4; ++m)
#pragma unroll
    for (int n = 0; n < 4; ++n)
#pragma unroll
      for (int j = 0; j < 4; ++j) {
        int r = r0 + m * 16 + j, col = c0 + n * 16;
        float v = (r == col) ? 0.f : acc[m][n][j] * dj[n];
        Cb[(long long)r * NN + col] = (bf16_t)v;
        tile[(rl0 + m * 16 + j) * 130 + cl0 + n * 16] = (bf16_t)v;
      }
  __syncthreads();
  int nl = t >> 5, rl = (t & 31) * 4;
#pragma unroll
  for (int vv = 0; vv < 16; ++vv) {
    int n_l = nl + vv * 8;
    bf16x4 o;
    o[0] = tile[(rl + 0) * 130 + n_l]; o[1] = tile[(rl + 1) * 130 + n_l];
    o[2] = tile[(rl + 2) * 130 + n_l]; o[3] = tile[(rl + 3) * 130 + n_l];
    *(bf16x4*)&Ct[(long long)(blockIdx.y * 128 + n_l) * NN + blockIdx.x * 128 + rl] = o;
  }
}

// ---------------- bf16 GEMM, 128x64 tile, ring-3, counted vmcnt, swizzle, fused epilogues ----------------

enum { EP_BRELU = 3, EP_BF32 = 4, EP_BF16O = 7, EP_XWDT = 8, EP_GCN = 9 };

template<int EP>
__global__ __launch_bounds__(256)
void k_gemm(const bf16_t* __restrict__ A, const bf16_t* __restrict__ B,
            void* __restrict__ Cv,
            const float* __restrict__ aux1, const float* __restrict__ aux2,
            bf16_t* __restrict__ aux3, const float* __restrict__ aux4,
            int N, int K, int lda, int ldb,
            long long zA, long long zB, long long zC) {
  __shared__ __align__(16) char smem[36864];
  bf16_t* As = (bf16_t*)smem;
  bf16_t* Bs = (bf16_t*)(smem + 24576);
  bf16_t* tile = (bf16_t*)smem;

  int cz = blockIdx.z;
  const bf16_t* Ab = A + cz * zA + (long long)blockIdx.x * 128 * lda;
  const bf16_t* Bb = B + cz * zB + (long long)blockIdx.y * 64 * ldb;

  int t = threadIdx.x, wid = t >> 6, lane = t & 63;
  int wr = wid >> 1, wc = wid & 1;
  f32x4 acc[4][2] = {};
  int frow = lane & 15;
  int fk_sw = (((lane >> 4) ^ ((frow >> 1) & 3)) << 3);
  int srow = t >> 2;
  int scol_sw = (((t & 3) ^ ((t >> 3) & 3)) << 3);
  int nt = K >> 5;

  auto STAGE = [&](int TT, int BUF) {
    long long kko = (long long)TT * 32 + scol_sw;
    const bf16_t* ga0 = Ab + (long long)srow * lda + kko;
    const bf16_t* ga1 = Ab + (long long)(64 + srow) * lda + kko;
    const bf16_t* gb0 = Bb + (long long)srow * ldb + kko;
    char* la = smem + BUF * 8192 + wid * 1024;
    char* lb = smem + 24576 + BUF * 4096 + wid * 1024;
    __builtin_amdgcn_global_load_lds((AS1 void*)ga0, (AS3 void*)la, 16, 0, 0);
    __builtin_amdgcn_global_load_lds((AS1 void*)ga1, (AS3 void*)(la + 4096), 16, 0, 0);
    __builtin_amdgcn_global_load_lds((AS1 void*)gb0, (AS3 void*)lb, 16, 0, 0);
  };
  auto COMPUTE = [&](int BUF) {
    bf16x8 af[4], bfr[2];
#pragma unroll
    for (int m = 0; m < 4; ++m)
      af[m] = *(const bf16x8*)&As[BUF * 4096 + (wr * 64 + m * 16 + frow) * 32 + fk_sw];
#pragma unroll
    for (int n = 0; n < 2; ++n)
      bfr[n] = *(const bf16x8*)&Bs[BUF * 2048 + (wc * 32 + n * 16 + frow) * 32 + fk_sw];
#pragma unroll
    for (int m = 0; m < 4; ++m)
#pragma unroll
      for (int n = 0; n < 2; ++n)
        acc[m][n] = __builtin_amdgcn_mfma_f32_16x16x32_bf16(af[m], bfr[n], acc[m][n], 0, 0, 0);
  };

  STAGE(0, 0); STAGE(1, 1); STAGE(2, 2);
  int slot = 0;
  for (int tt = 0; tt < nt; ++tt) {
    int rem = nt - 1 - tt;
    if (rem >= 2)      asm volatile("s_waitcnt vmcnt(6)" ::: "memory");
    else if (rem == 1) asm volatile("s_waitcnt vmcnt(3)" ::: "memory");
    else               asm volatile("s_waitcnt vmcnt(0)" ::: "memory");
    __builtin_amdgcn_s_barrier();
    __builtin_amdgcn_sched_barrier(0);
    COMPUTE(slot);
    __builtin_amdgcn_s_barrier();
    if (tt + 3 < nt) STAGE(tt + 3, slot);
    slot = (slot == 2) ? 0 : slot + 1;
  }
  __builtin_amdgcn_sched_barrier(0);

  int rl0 = wr * 64 + ((lane >> 4) << 2);
  int cl0 = wc * 32 + (lane & 15);
  int r0 = blockIdx.x * 128 + rl0;
  int c0 = blockIdx.y * 64 + cl0;

  if constexpr (EP == EP_BF16O) {
    bf16_t* Cb = (bf16_t*)Cv + cz * zC;
#pragma unroll
    for (int m = 0; m < 4; ++m)
#pragma unroll
      for (int n = 0; n < 2; ++n)
#pragma unroll
        for (int j = 0; j < 4; ++j)
          Cb[(long long)(r0 + m * 16 + j) * N + c0 + n * 16] = (bf16_t)acc[m][n][j];
  } else if constexpr (EP == EP_XWDT) {
    // XW (f32, row-major) + XWdT[c][f][i] = XW^T[f][i]*disv[c][i] via LDS transpose
    float* Cb = (float*)Cv;
#pragma unroll
    for (int m = 0; m < 4; ++m)
#pragma unroll
      for (int n = 0; n < 2; ++n)
#pragma unroll
        for (int j = 0; j < 4; ++j) {
          float v = acc[m][n][j];
          Cb[(long long)(r0 + m * 16 + j) * N + c0 + n * 16] = v;
          tile[(rl0 + m * 16 + j) * 65 + cl0 + n * 16] = (bf16_t)v;
        }
    __syncthreads();
    int nl = t >> 5, rl = (t & 31) * 4;
#pragma unroll
    for (int vv = 0; vv < 8; ++vv) {
      int n_l = nl + vv * 8;
      bf16x4 v4;
      v4[0] = tile[(rl + 0) * 65 + n_l]; v4[1] = tile[(rl + 1) * 65 + n_l];
      v4[2] = tile[(rl + 2) * 65 + n_l]; v4[3] = tile[(rl + 3) * 65 + n_l];
      int i0 = blockIdx.x * 128 + rl;
      long long row = (long long)(blockIdx.y * 64 + n_l) * NN + i0;
#pragma unroll
      for (int c = 0; c < 2; ++c) {
        float4 dv = *(const float4*)&aux2[c * NN + i0];  // disv
        bf16x4 o;
        o[0] = (bf16_t)((float)v4[0] * dv.x); o[1] = (bf16_t)((float)v4[1] * dv.y);
        o[2] = (bf16_t)((float)v4[2] * dv.z); o[3] = (bf16_t)((float)v4[3] * dv.w);
        *(bf16x4*)&aux3[(long long)c * WOUT * NN + row] = o;
      }
    }
  } else if constexpr (EP == EP_GCN) {
    // Xcat[n][cz*WOUT+f] = relu(cscal*(acc - Mdiag*dis*xw) + dis^2*xw + b)
    bf16_t* Cb = (bf16_t*)Cv;
    const float* XWp = aux1;
    const float* csp = aux2 + cz * NN;
    const float* dnp = aux2 + CC * NN + cz * NN;
    const float* mdp = aux2 + 2 * CC * NN + cz * NN;
    float bj[2];
#pragma unroll
    for (int n = 0; n < 2; ++n) bj[n] = aux4[c0 + n * 16];
#pragma unroll
    for (int m = 0; m < 4; ++m)
#pragma unroll
      for (int j = 0; j < 4; ++j) {
        int r = r0 + m * 16 + j;
        float csv = csp[r], dnv = dnp[r], mdv = mdp[r];
        float mdd = mdv * dnv, d2 = dnv * dnv;
#pragma unroll
        for (int n = 0; n < 2; ++n) {
          float xw = XWp[(long long)r * WOUT + c0 + n * 16];
          float v = fmaxf(csv * (acc[m][n][j] - mdd * xw) + d2 * xw + bj[n], 0.f);
          Cb[(long long)r * (CC * WOUT) + cz * WOUT + c0 + n * 16] = (bf16_t)v;
        }
      }
  } else if constexpr (EP == EP_BRELU) {
    bf16_t* Cb = (bf16_t*)Cv;
    float bj[2];
#pragma unroll
    for (int n = 0; n < 2; ++n) bj[n] = aux1[c0 + n * 16];
#pragma unroll
    for (int m = 0; m < 4; ++m)
#pragma unroll
      for (int n = 0; n < 2; ++n)
#pragma unroll
        for (int j = 0; j < 4; ++j)
          Cb[(long long)(r0 + m * 16 + j) * N + c0 + n * 16] =
              (bf16_t)fmaxf(acc[m][n][j] + bj[n], 0.f);
  } else { // EP_BF32
    float* Cb = (float*)Cv;
    float bj[2];
#pragma unroll
    for (int n = 0; n < 2; ++n) bj[n] = aux1[c0 + n * 16];
#pragma unroll
    for (int m = 0; m < 4; ++m)
#pragma unroll
      for (int n = 0; n < 2; ++n)
#pragma unroll
        for (int j = 0; j < 4; ++j)
          Cb[(long long)(r0 + m * 16 + j) * N + c0 + n * 16] = acc[m][n][j] + bj[n];
  }
}

// ---------------- launch ----------------

extern "C" void kernel_launch(void* const* d_in, const int* in_sizes, int n_in,
                              void* d_out, int out_size, void* d_ws, size_t ws_size,
                              hipStream_t stream) {
  const float* A    = (const float*)d_in[0];
  const float* X    = (const float*)d_in[1];
  const float* w0a  = (const float*)d_in[2];
  const float* w0b  = (const float*)d_in[3];
  const float* w1   = (const float*)d_in[4];
  const float* gcnw = (const float*)d_in[5];
  const float* gcnb = (const float*)d_in[6];
  const float* l1w  = (const float*)d_in[7];
  const float* l1b  = (const float*)d_in[8];
  const float* l2w  = (const float*)d_in[9];
  const float* l2b  = (const float*)d_in[10];
  float* out = (float*)d_out;

  char* p = (char*)d_ws;
  auto carve = [&](size_t bytes) -> char* {
    char* r = p; p += (bytes + 255) & ~(size_t)255; return r;
  };
  float*  svec  = (float*)carve((size_t)CC * NN * 4);
  float*  dinv1 = (float*)carve((size_t)CC * NN * 4);
  float*  m1    = (float*)carve((size_t)CC * NN * 4);
  float*  scal  = (float*)carve((size_t)3 * CC * NN * 4);  // cscal | disv | Mdiag
  float*  part  = (float*)carve((size_t)CC * 32 * NN * 4);
  bf16_t* S1    = (bf16_t*)carve((size_t)CC * N2 * 2);  // Ha -> {XWdT, Yt}
  bf16_t* HbT   = (bf16_t*)carve((size_t)CC * N2 * 2);
  bf16_t* Hb2T  = (bf16_t*)carve((size_t)CC * N2 * 2);
  bf16_t* Hn    = (bf16_t*)carve((size_t)CC * N2 * 2);
  bf16_t* HnT   = (bf16_t*)carve((size_t)CC * N2 * 2);
  bf16_t* Xb    = (bf16_t*)carve((size_t)NN * WIN * 2);
  bf16_t* gwT   = (bf16_t*)carve((size_t)WOUT * WIN * 2);
  bf16_t* l1wb  = (bf16_t*)carve((size_t)WOUT * CC * WOUT * 2);
  bf16_t* l2wb  = (bf16_t*)carve((size_t)WOUT * WOUT * 2);
  float*  XW    = (float*)carve((size_t)NN * WOUT * 4);
  bf16_t* Xcat  = (bf16_t*)carve((size_t)NN * CC * WOUT * 2);
  bf16_t* hb    = (bf16_t*)carve((size_t)NN * WOUT * 2);

  bf16_t* Ha = S1;
  bf16_t* XWdT = (bf16_t*)((char*)S1);                 // 2 MB
  bf16_t* Yt   = (bf16_t*)((char*)S1 + (2LL << 20));   // 2 MB
  float*  disv = scal + CC * NN;

  // combine (+merged prep)
  k_combine<<<1664, 256, 0, stream>>>(A, w0a, w0b, w1, Ha, HbT, Hb2T, part,
                                      X, l1w, l2w, gcnw, Xb, l1wb, l2wb, gwT);
  k_s_finish<<<16, 256, 0, stream>>>(part, svec);

  // layer 0: analytic degrees; GEMM1 (R8 config) fused normalize -> Hn + HnT
  k_deg<false><<<dim3(512, 2), 256, 0, stream>>>(svec, Ha, HbT, dinv1, m1, nullptr);
  k_gemmL<<<dim3(16, 16, 2), 256, 0, stream>>>(Ha, HbT, Hn, HnT, dinv1);

  // layer 1 scalars (packed: cscal | disv | Mdiag)
  k_deg<true><<<dim3(512, 2), 256, 0, stream>>>(m1, Hn, Hb2T,
                                                scal, scal + CC * NN, scal + 2 * CC * NN);

  // GCN via associativity: XW (+fused disv-scaled transpose -> XWdT both channels);
  // Yt = XWdT @ HnT^T; Xcat = gcn-epilogue(Hb2T @ Yt^T)
  k_gemm<EP_XWDT><<<dim3(16, 4, 1), 256, 0, stream>>>(
      Xb, gwT, XW, nullptr, disv, XWdT, nullptr, WOUT, WIN, WIN, WIN, 0, 0, 0);
  k_gemm<EP_BF16O><<<dim3(2, 32, 2), 256, 0, stream>>>(
      XWdT, HnT, Yt, nullptr, nullptr, nullptr, nullptr, NN, NN, NN, NN,
      (long long)WOUT * NN, N2, (long long)WOUT * NN);
  k_gemm<EP_GCN><<<dim3(16, 4, 2), 256, 0, stream>>>(
      Hb2T, Yt, Xcat, XW, scal, nullptr, gcnb, WOUT, NN, NN, NN,
      N2, (long long)WOUT * NN, 0);

  // MLP with fused bias(+relu)
  k_gemm<EP_BRELU><<<dim3(16, 4, 1), 256, 0, stream>>>(
      Xcat, l1wb, hb, l1b, nullptr, nullptr, nullptr, WOUT, CC * WOUT, CC * WOUT, CC * WOUT, 0, 0, 0);
  k_gemm<EP_BF32><<<dim3(16, 4, 1), 256, 0, stream>>>(
      hb, l2wb, out, l2b, nullptr, nullptr, nullptr, WOUT, WOUT, WOUT, WOUT, 0, 0, 0);
}